// Round 1
// baseline (324.572 us; speedup 1.0000x reference)
//
#include <hip/hip_runtime.h>
#include <hip/hip_fp16.h>

// Problem geometry (fixed by reference)
#define WINS 7
#define H 160
#define W 160
#define DD 96
#define HO 154          // H - WINS + 1
#define WO 154
#define DOUT 90
#define CSTRIDE (H*W*DD)   // per-(b,c) channel stride

// Tile: 8x8x16 outputs, all 4 classes per block
#define TH 8
#define TW 8
#define TD 16
#define IH 14            // TH + WINS - 1
#define IW 14
#define NCOL (IH * IW)   // 196
#define NDP 11           // dd-pairs per column (dd 0..21 used)
#define ID 24            // staged d extent per column (halfs; 3 x half8)
#define NV 6             // half4-items per column (fallback path)
#define NITEMS (NCOL * NV)   // 1176
#define HTILES 20
#define WTILES 20
#define DTILES 6
#define NBLK (DTILES * WTILES * 2 * HTILES)   // 4800

// sA: AoS [ih][wo][dp][plane] of half2. Row (ih) stride 293 half2 == 5 mod 32
// -> Phase-A write banks (5*ih + 3*dp) spread (<=3-way, was 4-way at stride 22);
//    Phase-B read banks (wo + 3*dp): exactly 2-way (free).
#define RSA 293          // 8*11*3 = 264 + 29 pad
// sb: AoS [col=ho*8+wo][pair][plane] of half2, col stride 13*3=39 == 7 mod 32
// -> Phase-C read banks (24*ho + 7*wo + 6*dq): <=3-way (was uniform 4-way,
//    even-banks-only at DPB2=24 where 96*ho == 0 mod 32).
#define SBP 13

struct alignas(8) Half4 { __half x, y, z, w; };

typedef const __attribute__((address_space(1))) unsigned int glds_g;
typedef __attribute__((address_space(3))) unsigned int glds_l;

static __device__ __forceinline__ __half2 u2h(unsigned int a) {
    __half2 r; __builtin_memcpy(&r, &a, 4); return r;
}
static __device__ __forceinline__ unsigned int h2u(__half2 v) {
    unsigned int r; __builtin_memcpy(&r, &v, 4); return r;
}
// p = max(v,0) per half; m = (sign clear) ? 1.0h : 0.0h per half.
static __device__ __forceinline__ void pmask(__half2 v, __half2& p, __half2& m) {
    const unsigned int bits = h2u(v);
    const unsigned int neg  = bits & 0x80008000u;
    const unsigned int full = (neg >> 15) * 0xFFFFu;          // 0xFFFF where negative
    p = u2h(bits & ~full);
    m = u2h(((~bits >> 15) & 0x00010001u) * 0x3C00u);         // 1.0h where sign clear
}

__device__ __forceinline__ float sval(float c0, float c1, float c2) {
    // c0=S_m, c1=S_tm, c2=S_t2m over the 343-voxel window; t = m?sigmoid:0.5
    const float S_t  = c1 + 0.5f  * (343.0f - c0);
    const float S_t2 = c2 + 0.25f * (343.0f - c0);
    const float inv  = 1.0f / 343.0f;
    const float ux   = S_t  * inv;
    const float uy   = c0   * inv;
    const float uxx  = S_t2 * inv;
    const float uxy  = c1   * inv;
    const float covn = 49.0f / 48.0f;   // WIN^2/(WIN^2-1)
    const float cc   = 0.00045f;        // (0.03*data_range)^2/2, data_range==1
    const float vx  = covn * (uxx - ux * ux);
    const float vy  = covn * (uy  - uy * uy);
    const float vxy = covn * (uxy - ux * uy);
    return (vxy + cc) * __builtin_amdgcn_rcpf(vx * vy + cc);   // den >= ~3e-4
}

// Pre-pass: v = (y==c ? +sigmoid(x) : -sigmoid(x)) as f16.
// Also zeroes acc + ticket (replaces the hipMemsetAsync dispatch).
__global__ __launch_bounds__(256)
void sigmoid_prepass(const float* __restrict__ x,
                     const int* __restrict__ y,
                     __half* __restrict__ xs,
                     double* __restrict__ acc) {
    if (blockIdx.x == 0 && blockIdx.y == 0 && threadIdx.x == 0) {
        acc[0] = 0.0;                                  // sum
        ((unsigned long long*)acc)[1] = 0ull;          // ticket
    }
    const int b  = blockIdx.y;
    const int qv = blockIdx.x * 256 + threadIdx.x;    // 0..614399
    const int off = 4 * qv;
    const int4 yv = *(const int4*)(y + (size_t)b * CSTRIDE + off);
#pragma unroll
    for (int c = 0; c < 4; c++) {
        const size_t xo = ((size_t)(b * 4 + c)) * CSTRIDE + off;
        const float4 xv = *(const float4*)(x + xo);
        const float s0 = 1.0f / (1.0f + __expf(-xv.x));
        const float s1 = 1.0f / (1.0f + __expf(-xv.y));
        const float s2 = 1.0f / (1.0f + __expf(-xv.z));
        const float s3 = 1.0f / (1.0f + __expf(-xv.w));
        Half4 hv;
        hv.x = __float2half((yv.x == c) ? s0 : -s0);
        hv.y = __float2half((yv.y == c) ? s1 : -s1);
        hv.z = __float2half((yv.z == c) ? s2 : -s2);
        hv.w = __float2half((yv.w == c) ? s3 : -s3);
        *(Half4*)(xs + xo) = hv;
    }
}

// (256,5): (256,6) pinned the allocator to 40 VGPR -> massive scratch spill
// (R9/R10). (256,5) -> 48 VGPR, zero spill; HW occupancy is LDS-capped.
template <bool PRE>
__global__ __launch_bounds__(256, 5)
void structure_loss_main(const float* __restrict__ x,
                         const int* __restrict__ y,
                         const __half* __restrict__ xs,
                         double* __restrict__ acc,
                         float* __restrict__ out) {
    // W-window sums, AoS: 14*293 half2 = 16,408 B
    __shared__ __half2 sA2[IH * RSA];
    // vs (phase 0/A input) and sb (phase B/C) never live together: 9,984 B
    __shared__ union alignas(16) {
        __half  vs[NCOL * ID];            // v = +/- sigma, f16 (lane-linear!)
        __half2 sb2[TH * TW * SBP * 3];   // H-window sums, AoS [col][pair][pl]
    } u;
    __shared__ unsigned int yb[NCOL * 2];   // fallback only: 2-bit packed y
    __shared__ float wsum[4];

    const int dt = blockIdx.x;                 // 0..5
    const int wt = blockIdx.y;                 // 0..19
    const int z  = blockIdx.z;                 // 0..39 = b*HTILES + ht
    const int b  = z / HTILES;
    const int ht = z - b * HTILES;

    const int h0 = ht * TH, w0 = wt * TW, d0 = dt * TD;
    const int* yc = y + (size_t)b * (size_t)CSTRIDE;
    const int t = threadIdx.x;

    if (!PRE) {
        // ---- Phase Y (fallback): stage y tile 2-bit packed ----
        for (int i = t; i < NCOL * 2; i += 256) {
            const int col = i >> 1, hf = i & 1;
            const int ih = col / IW, iw = col - ih * IW;
            const int h = min(h0 + ih, H - 1);
            const int w = min(w0 + iw, W - 1);
            const size_t cb = (size_t)(h * W + w) * DD;
            const int dstart = d0 + 12 * hf;
            unsigned int pk = 0u;
#pragma unroll
            for (int j3 = 0; j3 < 3; j3++) {
                const int dbase = dstart + 4 * j3;
                if (dbase < DD) {
                    const int4 yv = *(const int4*)(yc + cb + dbase);
                    pk |= (unsigned)(yv.x & 3) << (2 * (4 * j3 + 0));
                    pk |= (unsigned)(yv.y & 3) << (2 * (4 * j3 + 1));
                    pk |= (unsigned)(yv.z & 3) << (2 * (4 * j3 + 2));
                    pk |= (unsigned)(yv.w & 3) << (2 * (4 * j3 + 3));
                }
            }
            yb[i] = pk;
        }
        __syncthreads();
    }

    float lsum = 0.f;

    for (int cl = 0; cl < 4; cl++) {
        if (PRE) {
            // ---- Phase 0 (PRE): async global->LDS, dwordx4. vs byte addr is
            // exactly 16*i for item i = t + 256*k, i.e. wave-uniform base +
            // lane*16 -> legal global_load_lds destination. Out-of-range d is
            // clamped to DD-8 (duplicate, finite data): contaminates only
            // dd>=16-local of the dt=5 tile, which feeds only dg>=DOUT
            // outputs discarded by the Phase-C guard.
            const __half* xsc = xs + ((size_t)b * 4 + cl) * (size_t)CSTRIDE;
#pragma unroll
            for (int k = 0; k < 3; k++) {              // 588 items, 16 B each
                const int i = t + 256 * k;
                if (i < NCOL * 3) {
                    const int col = i / 3, q = i - col * 3;
                    const int ih = col / IW, iw = col - ih * IW;
                    const int h = min(h0 + ih, H - 1);
                    const int w = min(w0 + iw, W - 1);
                    const int dbase = min(d0 + 8 * q, DD - 8);
                    const __half* gp = xsc + (size_t)((h * W + w) * DD + dbase);
                    __half* lp = &u.vs[col * ID + 8 * q];
                    __builtin_amdgcn_global_load_lds((glds_g*)(const void*)gp,
                                                     (glds_l*)(void*)lp,
                                                     16, 0, 0);
                }
            }
        } else {
            // ---- Phase 0 (fallback): stage x, compute sigmoid, fuse y ----
            const float* xc = x + ((size_t)b * 4 + cl) * (size_t)CSTRIDE;
#pragma unroll
            for (int k = 0; k < 5; k++) {
                const int i = t + 256 * k;
                if (i < NITEMS) {
                    const int col = i / NV, q = i - col * NV;
                    const int ih = col / IW, iw = col - ih * IW;
                    const int h = min(h0 + ih, H - 1);
                    const int w = min(w0 + iw, W - 1);
                    const int dbase = d0 + 4 * q;
                    Half4 hv;
                    hv.x = hv.y = hv.z = hv.w = __float2half(0.f);
                    if (dbase < DD) {
                        const float4 xv = *(const float4*)(xc + (h * W + w) * DD + dbase);
                        const int wsel = (q >= 3) ? 1 : 0;
                        const unsigned int pk =
                            yb[col * 2 + wsel] >> (8 * (q - 3 * wsel));
                        const float s0 = 1.0f / (1.0f + __expf(-xv.x));
                        const float s1 = 1.0f / (1.0f + __expf(-xv.y));
                        const float s2 = 1.0f / (1.0f + __expf(-xv.z));
                        const float s3 = 1.0f / (1.0f + __expf(-xv.w));
                        hv.x = __float2half(((int)((pk >> 0) & 3u) == cl) ? s0 : -s0);
                        hv.y = __float2half(((int)((pk >> 2) & 3u) == cl) ? s1 : -s1);
                        hv.z = __float2half(((int)((pk >> 4) & 3u) == cl) ? s2 : -s2);
                        hv.w = __float2half(((int)((pk >> 6) & 3u) == cl) ? s3 : -s3);
                    }
                    *(Half4*)&u.vs[col * ID + 4 * q] = hv;
                }
            }
        }
        __syncthreads();

        // ---- Phase A: W-window, packed f16 over dd-pairs. 154 items (ih,dp) ----
        if (t < IH * NDP) {
            const int ih = t / NDP, dp = t - ih * NDP;
            const int dd = 2 * dp;
            const __half2 z2 = __float2half2_rn(0.f);
            __half2 v2[IW];
            const int vbase = ih * IW * ID + dd;
#pragma unroll
            for (int iw = 0; iw < IW; iw++)
                v2[iw] = *(const __half2*)&u.vs[vbase + iw * ID];
            __half2 sm = z2, sp = z2, sq = z2;
#pragma unroll
            for (int iw = 0; iw < WINS; iw++) {
                __half2 p, m;
                pmask(v2[iw], p, m);
                sm = __hadd2(sm, m);
                sp = __hadd2(sp, p);
                sq = __hfma2(p, v2[iw], sq);
            }
            int o = ih * RSA + dp * 3;                 // wo = 0
            sA2[o] = sm; sA2[o + 1] = sp; sA2[o + 2] = sq;
#pragma unroll
            for (int wo = 1; wo < TW; wo++) {
                const __half2 a = v2[wo + 6], bb = v2[wo - 1];
                __half2 pa, ma, pb, mb;
                pmask(a, pa, ma);
                pmask(bb, pb, mb);
                sm = __hadd2(sm, __hsub2(ma, mb));
                sp = __hadd2(sp, __hsub2(pa, pb));
                sq = __hadd2(sq, __hsub2(__hmul2(pa, a), __hmul2(pb, bb)));
                o += NDP * 3;                          // +33
                sA2[o] = sm; sA2[o + 1] = sp; sA2[o + 2] = sq;
            }
        }
        __syncthreads();   // sA ready; vs reads retired before sb overwrites union

        // ---- Phase B: H-window, packed f16 over dd-pairs. 176 items ----
        if (t < 2 * TW * NDP) {
            const int dp = t % NDP;
            const int r  = t / NDP;
            const int wo = r & 7;
            const int ho0 = (r >> 3) * 4;              // 0 or 4
            __half2 a0[10], a1[10], a2[10];
#pragma unroll
            for (int k = 0; k < 10; k++) {
                const int idx = (ho0 + k) * RSA + (wo * NDP + dp) * 3;
                a0[k] = sA2[idx];
                a1[k] = sA2[idx + 1];
                a2[k] = sA2[idx + 2];
            }
            __half2 s0 = a0[0], s1 = a1[0], s2 = a2[0];
#pragma unroll
            for (int k = 1; k < WINS; k++) {
                s0 = __hadd2(s0, a0[k]);
                s1 = __hadd2(s1, a1[k]);
                s2 = __hadd2(s2, a2[k]);
            }
            int o = ((ho0 * TW + wo) * SBP + dp) * 3;
            u.sb2[o] = s0; u.sb2[o + 1] = s1; u.sb2[o + 2] = s2;
#pragma unroll
            for (int k = 1; k < 4; k++) {
                s0 = __hadd2(s0, __hsub2(a0[k + 6], a0[k - 1]));
                s1 = __hadd2(s1, __hsub2(a1[k + 6], a1[k - 1]));
                s2 = __hadd2(s2, __hsub2(a2[k + 6], a2[k - 1]));
                o += TW * SBP * 3;                     // +312
                u.sb2[o] = s0; u.sb2[o + 1] = s1; u.sb2[o + 2] = s2;
            }
        }
        __syncthreads();

        // ---- Phase C: D-window, slide 4 outputs. 256 threads (ho,wo,dq) ----
        {
            const int dq = t & 3;                  // d outputs dq*4 .. dq*4+3
            const int wo = (t >> 2) & 7;
            const int ho = t >> 5;
            const int hg = h0 + ho, wg = w0 + wo;
            if (hg < HO && wg < WO) {
                const int colb = (ho * TW + wo) * SBP;
                float b0[10], b1[10], b2[10];
#pragma unroll
                for (int k = 0; k < 5; k++) {
                    const int rd = (colb + 2 * dq + k) * 3;
                    float2 f;
                    f = __half22float2(u.sb2[rd + 0]);
                    b0[2 * k] = f.x; b0[2 * k + 1] = f.y;
                    f = __half22float2(u.sb2[rd + 1]);
                    b1[2 * k] = f.x; b1[2 * k + 1] = f.y;
                    f = __half22float2(u.sb2[rd + 2]);
                    b2[2 * k] = f.x; b2[2 * k + 1] = f.y;
                }
                float s0 = 0.f, s1 = 0.f, s2 = 0.f;
#pragma unroll
                for (int k = 0; k < WINS; k++) { s0 += b0[k]; s1 += b1[k]; s2 += b2[k]; }
                const int dg = d0 + dq * 4;
#pragma unroll
                for (int k = 0; k < 4; k++) {
                    if (k > 0) {
                        s0 += b0[k + 6] - b0[k - 1];
                        s1 += b1[k + 6] - b1[k - 1];
                        s2 += b2[k + 6] - b2[k - 1];
                    }
                    if (dg + k < DOUT) lsum += sval(s0, s1, s2);
                }
            }
        }
        __syncthreads();   // retire sb reads before next class overwrites union
    }

    // wave(64) shuffle reduce, then cross-wave via LDS, one atomic per block,
    // then fused finalize: last block (device-scope ticket) writes the output.
#pragma unroll
    for (int off = 32; off > 0; off >>= 1) lsum += __shfl_down(lsum, off, 64);
    const int wave = t >> 6;
    if ((t & 63) == 0) wsum[wave] = lsum;
    __syncthreads();
    if (t == 0) {
        const double s = (double)(wsum[0] + wsum[1] + wsum[2] + wsum[3]);
        atomicAdd(acc, s);
        __threadfence();
        unsigned long long* tk = (unsigned long long*)(acc + 1);
        if (atomicAdd(tk, 1ull) == (unsigned long long)(NBLK - 1)) {
            __threadfence();
            const double tot = atomicAdd(acc, 0.0);    // device-scope read
            out[0] = 1.0f - (float)(tot / 17075520.0); // 8*154*154*90
        }
    }
}

extern "C" void kernel_launch(void* const* d_in, const int* in_sizes, int n_in,
                              void* d_out, int out_size, void* d_ws, size_t ws_size,
                              hipStream_t stream) {
    const float* x = (const float*)d_in[0];
    const int*   y = (const int*)d_in[1];
    double* acc = (double*)d_ws;
    __half* xs = (__half*)((char*)d_ws + 16);

    const size_t need = 16 + (size_t)8 * CSTRIDE * sizeof(__half);   // ~39.3 MB
    dim3 grid(DTILES, WTILES, 2 * HTILES);   // (6, 20, 40) = 4,800 blocks

    if (ws_size >= need) {
        // 2 dispatches total: prepass zeroes acc/ticket, main finalizes.
        sigmoid_prepass<<<dim3(2400, 2), 256, 0, stream>>>(x, y, xs, acc);
        structure_loss_main<true><<<grid, 256, 0, stream>>>(x, y, xs, acc,
                                                            (float*)d_out);
    } else {
        (void)hipMemsetAsync(d_ws, 0, 16, stream);
        structure_loss_main<false><<<grid, 256, 0, stream>>>(x, y, xs, acc,
                                                             (float*)d_out);
    }
}

// Round 2
// 209.572 us; speedup vs baseline: 1.5487x; 1.5487x over previous
//
#include <hip/hip_runtime.h>
#include <hip/hip_fp16.h>

// Problem geometry (fixed by reference)
#define WINS 7
#define H 160
#define W 160
#define DD 96
#define HO 154          // H - WINS + 1
#define WO 154
#define DOUT 90
#define CSTRIDE (H*W*DD)   // per-(b,c) channel stride

// Tile: 8x8x16 outputs, all 4 classes per block
#define TH 8
#define TW 8
#define TD 16
#define IH 14            // TH + WINS - 1
#define IW 14
#define NCOL (IH * IW)   // 196
#define IDU 22           // used d extent = TD + WINS - 1 (even)
#define NDP 11           // dd-pairs per column
#define ID 24            // staged d extent per column (halfs; 3 x half8)
#define NV 6             // half4-items per column (fallback path)
#define NITEMS (NCOL * NV)   // 1176
#define HTILES 20
#define WTILES 20
#define DTILES 6
// DPB2=24 made Phase-C banks (12*wo+2*dq+k) mod 32: ho*96 == 0 mod 32 -> the
// ho term vanished, even banks only, uniform 4-way conflict on every Phase-C
// read. DPB2=26 gives (8*ho+13*wo+2*dq+k) mod 32: mixed parity, <=2-3-way
// (2-way is free). Still even (half2-aligned); LDS +576 B, still 6 blocks/CU.
#define DPB2 26          // sb plane dd-stride in halfs (even, >=22)

struct alignas(8) Half4 { __half x, y, z, w; };

static __device__ __forceinline__ __half2 u2h(unsigned int a) {
    __half2 r; __builtin_memcpy(&r, &a, 4); return r;
}
static __device__ __forceinline__ unsigned int h2u(__half2 v) {
    unsigned int r; __builtin_memcpy(&r, &v, 4); return r;
}
// p = max(v,0) per half; m = (sign clear) ? 1.0h : 0.0h per half.
// v = +sigma (mask on), -sigma (mask off), or +0 (padding; feeds only
// discarded outputs dg>=DOUT, so m=1 there is harmless).
static __device__ __forceinline__ void pmask(__half2 v, __half2& p, __half2& m) {
    const unsigned int bits = h2u(v);
    const unsigned int neg  = bits & 0x80008000u;
    const unsigned int full = (neg >> 15) * 0xFFFFu;          // 0xFFFF where negative
    p = u2h(bits & ~full);
    m = u2h(((~bits >> 15) & 0x00010001u) * 0x3C00u);         // 1.0h where sign clear
}

__device__ __forceinline__ float sval(float c0, float c1, float c2) {
    // c0=S_m, c1=S_tm, c2=S_t2m over the 343-voxel window; t = m?sigmoid:0.5
    const float S_t  = c1 + 0.5f  * (343.0f - c0);
    const float S_t2 = c2 + 0.25f * (343.0f - c0);
    const float inv  = 1.0f / 343.0f;
    const float ux   = S_t  * inv;
    const float uy   = c0   * inv;
    const float uxx  = S_t2 * inv;
    const float uxy  = c1   * inv;
    const float covn = 49.0f / 48.0f;   // WIN^2/(WIN^2-1)
    const float cc   = 0.00045f;        // (0.03*data_range)^2/2, data_range==1
    const float vx  = covn * (uxx - ux * ux);
    const float vy  = covn * (uy  - uy * uy);
    const float vxy = covn * (uxy - ux * uy);
    return (vxy + cc) * __builtin_amdgcn_rcpf(vx * vy + cc);   // den >= ~3e-4
}

// Pre-pass: v = (y==c ? +sigmoid(x) : -sigmoid(x)) as f16, one value per
// (channel, voxel). Removes the 4.6x halo-amplified transcendental recompute
// from the main kernel. Also zeroes acc (replaces the hipMemsetAsync dispatch;
// kernel-boundary ordering on the stream makes the store visible to main).
__global__ __launch_bounds__(256)
void sigmoid_prepass(const float* __restrict__ x,
                     const int* __restrict__ y,
                     __half* __restrict__ xs,
                     double* __restrict__ acc) {
    if (blockIdx.x == 0 && blockIdx.y == 0 && threadIdx.x == 0) acc[0] = 0.0;
    const int b  = blockIdx.y;
    const int qv = blockIdx.x * 256 + threadIdx.x;    // 0..614399
    const int off = 4 * qv;
    const int4 yv = *(const int4*)(y + (size_t)b * CSTRIDE + off);
#pragma unroll
    for (int c = 0; c < 4; c++) {
        const size_t xo = ((size_t)(b * 4 + c)) * CSTRIDE + off;
        const float4 xv = *(const float4*)(x + xo);
        const float s0 = 1.0f / (1.0f + __expf(-xv.x));
        const float s1 = 1.0f / (1.0f + __expf(-xv.y));
        const float s2 = 1.0f / (1.0f + __expf(-xv.z));
        const float s3 = 1.0f / (1.0f + __expf(-xv.w));
        Half4 hv;
        hv.x = __float2half((yv.x == c) ? s0 : -s0);
        hv.y = __float2half((yv.y == c) ? s1 : -s1);
        hv.z = __float2half((yv.z == c) ? s2 : -s2);
        hv.w = __float2half((yv.w == c) ? s3 : -s3);
        *(Half4*)(xs + xo) = hv;
    }
}

// (256,5): (256,6) pinned the allocator to 40 VGPR -> massive scratch spill
// (R9/R10). (256,5) -> 48 VGPR, zero spill; HW occupancy is LDS-capped.
template <bool PRE>
__global__ __launch_bounds__(256, 5)
void structure_loss_main(const float* __restrict__ x,
                         const int* __restrict__ y,
                         const __half* __restrict__ xs,
                         double* __restrict__ acc) {
    // W-window sums, f16 SoA planes [ih][wo][dd]: 3 * 14*8*22*2 = 14,784 B
    __shared__ __half sA0[IH * TW * IDU];
    __shared__ __half sA1[IH * TW * IDU];
    __shared__ __half sA2[IH * TW * IDU];
    // vs (phase 0/A input) and sb (phase B/C) never live together: 9,984 B
    __shared__ union alignas(16) {
        __half vs[NCOL * ID];            // v = +/- sigma, f16
        struct {
            __half b0[TH * TW * DPB2];   // S_m   H-window sums
            __half b1[TH * TW * DPB2];   // S_tm
            __half b2[TH * TW * DPB2];   // S_t2m
        } sb;
    } u;
    __shared__ unsigned int yb[NCOL * 2];   // fallback only: 2-bit packed y
    __shared__ float wsum[4];

    const int dt = blockIdx.x;                 // 0..5
    const int wt = blockIdx.y;                 // 0..19
    const int z  = blockIdx.z;                 // 0..39 = b*HTILES + ht
    const int b  = z / HTILES;
    const int ht = z - b * HTILES;

    const int h0 = ht * TH, w0 = wt * TW, d0 = dt * TD;
    const int* yc = y + (size_t)b * (size_t)CSTRIDE;
    const int t = threadIdx.x;

    if (!PRE) {
        // ---- Phase Y (fallback): stage y tile 2-bit packed ----
        for (int i = t; i < NCOL * 2; i += 256) {
            const int col = i >> 1, hf = i & 1;
            const int ih = col / IW, iw = col - ih * IW;
            const int h = min(h0 + ih, H - 1);
            const int w = min(w0 + iw, W - 1);
            const size_t cb = (size_t)(h * W + w) * DD;
            const int dstart = d0 + 12 * hf;
            unsigned int pk = 0u;
#pragma unroll
            for (int j3 = 0; j3 < 3; j3++) {
                const int dbase = dstart + 4 * j3;
                if (dbase < DD) {
                    const int4 yv = *(const int4*)(yc + cb + dbase);
                    pk |= (unsigned)(yv.x & 3) << (2 * (4 * j3 + 0));
                    pk |= (unsigned)(yv.y & 3) << (2 * (4 * j3 + 1));
                    pk |= (unsigned)(yv.z & 3) << (2 * (4 * j3 + 2));
                    pk |= (unsigned)(yv.w & 3) << (2 * (4 * j3 + 3));
                }
            }
            yb[i] = pk;
        }
        __syncthreads();
    }

    float lsum = 0.f;

    for (int cl = 0; cl < 4; cl++) {
        if (PRE) {
            // ---- Phase 0 (PRE): pure Half8 copy of precomputed +/-sigma ----
            const __half* xsc = xs + ((size_t)b * 4 + cl) * (size_t)CSTRIDE;
#pragma unroll
            for (int k = 0; k < 3; k++) {              // 588 items, Half8 each
                const int i = t + 256 * k;
                if (i < NCOL * 3) {
                    const int col = i / 3, q = i - col * 3;
                    const int ih = col / IW, iw = col - ih * IW;
                    const int h = min(h0 + ih, H - 1);
                    const int w = min(w0 + iw, W - 1);
                    const int dbase = d0 + 8 * q;
                    uint4 vv = make_uint4(0u, 0u, 0u, 0u);   // +0 padding
                    if (dbase < DD)
                        vv = *(const uint4*)(xsc + (h * W + w) * DD + dbase);
                    *(uint4*)&u.vs[col * ID + 8 * q] = vv;
                }
            }
        } else {
            // ---- Phase 0 (fallback): stage x, compute sigmoid, fuse y ----
            const float* xc = x + ((size_t)b * 4 + cl) * (size_t)CSTRIDE;
#pragma unroll
            for (int k = 0; k < 5; k++) {
                const int i = t + 256 * k;
                if (i < NITEMS) {
                    const int col = i / NV, q = i - col * NV;
                    const int ih = col / IW, iw = col - ih * IW;
                    const int h = min(h0 + ih, H - 1);
                    const int w = min(w0 + iw, W - 1);
                    const int dbase = d0 + 4 * q;
                    Half4 hv;
                    hv.x = hv.y = hv.z = hv.w = __float2half(0.f);
                    if (dbase < DD) {
                        const float4 xv = *(const float4*)(xc + (h * W + w) * DD + dbase);
                        const int wsel = (q >= 3) ? 1 : 0;
                        const unsigned int pk =
                            yb[col * 2 + wsel] >> (8 * (q - 3 * wsel));
                        const float s0 = 1.0f / (1.0f + __expf(-xv.x));
                        const float s1 = 1.0f / (1.0f + __expf(-xv.y));
                        const float s2 = 1.0f / (1.0f + __expf(-xv.z));
                        const float s3 = 1.0f / (1.0f + __expf(-xv.w));
                        hv.x = __float2half(((int)((pk >> 0) & 3u) == cl) ? s0 : -s0);
                        hv.y = __float2half(((int)((pk >> 2) & 3u) == cl) ? s1 : -s1);
                        hv.z = __float2half(((int)((pk >> 4) & 3u) == cl) ? s2 : -s2);
                        hv.w = __float2half(((int)((pk >> 6) & 3u) == cl) ? s3 : -s3);
                    }
                    *(Half4*)&u.vs[col * ID + 4 * q] = hv;
                }
            }
        }
        __syncthreads();

        // ---- Phase A: W-window, packed f16 over dd-pairs. 154 items (ih,dp) ----
        if (t < IH * NDP) {
            const int ih = t / NDP, dp = t - ih * NDP;
            const int dd = 2 * dp;
            const __half2 z2 = __float2half2_rn(0.f);
            __half2 v2[IW];
            const int vbase = ih * IW * ID + dd;
#pragma unroll
            for (int iw = 0; iw < IW; iw++)
                v2[iw] = *(const __half2*)&u.vs[vbase + iw * ID];
            __half2 sm = z2, sp = z2, sq = z2;
#pragma unroll
            for (int iw = 0; iw < WINS; iw++) {
                __half2 p, m;
                pmask(v2[iw], p, m);
                sm = __hadd2(sm, m);
                sp = __hadd2(sp, p);
                sq = __hfma2(p, v2[iw], sq);
            }
            int o = (ih * TW) * IDU + dd;
            *(__half2*)&sA0[o] = sm;
            *(__half2*)&sA1[o] = sp;
            *(__half2*)&sA2[o] = sq;
#pragma unroll
            for (int wo = 1; wo < TW; wo++) {
                const __half2 a = v2[wo + 6], bb = v2[wo - 1];
                __half2 pa, ma, pb, mb;
                pmask(a, pa, ma);
                pmask(bb, pb, mb);
                sm = __hadd2(sm, __hsub2(ma, mb));
                sp = __hadd2(sp, __hsub2(pa, pb));
                sq = __hadd2(sq, __hsub2(__hmul2(pa, a), __hmul2(pb, bb)));
                o += IDU;
                *(__half2*)&sA0[o] = sm;
                *(__half2*)&sA1[o] = sp;
                *(__half2*)&sA2[o] = sq;
            }
        }
        __syncthreads();   // sA ready; vs reads retired before sb overwrites union

        // ---- Phase B: H-window, packed f16 over dd-pairs. 176 items ----
        if (t < 2 * TW * NDP) {
            const int dp = t % NDP;
            const int r  = t / NDP;
            const int wo = r & 7;
            const int ho0 = (r >> 3) * 4;          // 0 or 4
            const int dd = 2 * dp;
            __half2 a0[10], a1[10], a2[10];
#pragma unroll
            for (int k = 0; k < 10; k++) {
                const int idx = ((ho0 + k) * TW + wo) * IDU + dd;
                a0[k] = *(const __half2*)&sA0[idx];
                a1[k] = *(const __half2*)&sA1[idx];
                a2[k] = *(const __half2*)&sA2[idx];
            }
            __half2 s0 = a0[0], s1 = a1[0], s2 = a2[0];
#pragma unroll
            for (int k = 1; k < WINS; k++) {
                s0 = __hadd2(s0, a0[k]);
                s1 = __hadd2(s1, a1[k]);
                s2 = __hadd2(s2, a2[k]);
            }
            int o = (ho0 * TW + wo) * DPB2 + dd;
            *(__half2*)&u.sb.b0[o] = s0;
            *(__half2*)&u.sb.b1[o] = s1;
            *(__half2*)&u.sb.b2[o] = s2;
#pragma unroll
            for (int k = 1; k < 4; k++) {
                s0 = __hadd2(s0, __hsub2(a0[k + 6], a0[k - 1]));
                s1 = __hadd2(s1, __hsub2(a1[k + 6], a1[k - 1]));
                s2 = __hadd2(s2, __hsub2(a2[k + 6], a2[k - 1]));
                o += TW * DPB2;
                *(__half2*)&u.sb.b0[o] = s0;
                *(__half2*)&u.sb.b1[o] = s1;
                *(__half2*)&u.sb.b2[o] = s2;
            }
        }
        __syncthreads();

        // ---- Phase C: D-window, slide 4 outputs. 256 threads (ho,wo,dq) ----
        {
            const int dq = t & 3;                  // d outputs dq*4 .. dq*4+3
            const int wo = (t >> 2) & 7;
            const int ho = t >> 5;
            const int hg = h0 + ho, wg = w0 + wo;
            if (hg < HO && wg < WO) {
                const int base = (ho * TW + wo) * DPB2 + dq * 4;   // even -> aligned
                float b0[10], b1[10], b2[10];
#pragma unroll
                for (int k = 0; k < 5; k++) {
                    float2 f;
                    f = __half22float2(*(const __half2*)&u.sb.b0[base + 2 * k]);
                    b0[2 * k] = f.x; b0[2 * k + 1] = f.y;
                    f = __half22float2(*(const __half2*)&u.sb.b1[base + 2 * k]);
                    b1[2 * k] = f.x; b1[2 * k + 1] = f.y;
                    f = __half22float2(*(const __half2*)&u.sb.b2[base + 2 * k]);
                    b2[2 * k] = f.x; b2[2 * k + 1] = f.y;
                }
                float s0 = 0.f, s1 = 0.f, s2 = 0.f;
#pragma unroll
                for (int k = 0; k < WINS; k++) { s0 += b0[k]; s1 += b1[k]; s2 += b2[k]; }
                const int dg = d0 + dq * 4;
#pragma unroll
                for (int k = 0; k < 4; k++) {
                    if (k > 0) {
                        s0 += b0[k + 6] - b0[k - 1];
                        s1 += b1[k + 6] - b1[k - 1];
                        s2 += b2[k + 6] - b2[k - 1];
                    }
                    if (dg + k < DOUT) lsum += sval(s0, s1, s2);
                }
            }
        }
        __syncthreads();   // retire sb reads before next class overwrites union
    }

    // wave(64) shuffle reduce, then cross-wave via LDS, one atomic per block
#pragma unroll
    for (int off = 32; off > 0; off >>= 1) lsum += __shfl_down(lsum, off, 64);
    const int wave = t >> 6;
    if ((t & 63) == 0) wsum[wave] = lsum;
    __syncthreads();
    if (t == 0) {
        const float s = wsum[0] + wsum[1] + wsum[2] + wsum[3];
        atomicAdd(acc, (double)s);
    }
}

__global__ void structure_loss_finalize(const double* __restrict__ acc,
                                        float* __restrict__ out) {
    out[0] = 1.0f - (float)(acc[0] / 17075520.0);   // 8*154*154*90
}

extern "C" void kernel_launch(void* const* d_in, const int* in_sizes, int n_in,
                              void* d_out, int out_size, void* d_ws, size_t ws_size,
                              hipStream_t stream) {
    const float* x = (const float*)d_in[0];
    const int*   y = (const int*)d_in[1];
    double* acc = (double*)d_ws;
    __half* xs = (__half*)((char*)d_ws + 16);

    const size_t need = 16 + (size_t)8 * CSTRIDE * sizeof(__half);   // ~39.3 MB
    dim3 grid(DTILES, WTILES, 2 * HTILES);   // (6, 20, 40) = 4,800 blocks

    if (ws_size >= need) {
        // prepass zeroes acc -> 3 dispatches total
        sigmoid_prepass<<<dim3(2400, 2), 256, 0, stream>>>(x, y, xs, acc);
        structure_loss_main<true><<<grid, 256, 0, stream>>>(x, y, xs, acc);
    } else {
        (void)hipMemsetAsync(d_ws, 0, sizeof(double), stream);
        structure_loss_main<false><<<grid, 256, 0, stream>>>(x, y, xs, acc);
    }
    structure_loss_finalize<<<1, 1, 0, stream>>>(acc, (float*)d_out);
}

// Round 3
// 199.275 us; speedup vs baseline: 1.6288x; 1.0517x over previous
//
#include <hip/hip_runtime.h>
#include <hip/hip_fp16.h>

// Problem geometry (fixed by reference)
#define WINS 7
#define H 160
#define W 160
#define DD 96
#define HO 154          // H - WINS + 1
#define WO 154
#define DOUT 90
#define CSTRIDE (H*W*DD)   // per-(b,c) channel stride

// Tile: 8x8x24 outputs, all 4 classes sequentially per block.
// TD=24: d0*2B in {0,48,96,144} -> 16B-aligned uint4 staging for every tile
// (last tile re-bases to dstage=64, uniform doff=8). 4 d-tiles vs 6:
// -33% blocks/barriers, -25% HBM line touches, staged d-halo 120 vs 144.
#define TH 8
#define TW 8
#define TD 24
#define IH 14            // TH + WINS - 1
#define IW 14
#define NCOL (IH * IW)   // 196
#define IDS 32           // staged halfs per column (4 x uint4, 16B aligned)
#define IDW 30           // window extent used = TD + WINS - 1
#define NDP 15           // dd-pairs per column
#define SAS 30           // sA row stride in halfs (even, = IDW, no pad)
#define SBC 49           // sb col stride in half2 units (odd -> ho spreads banks)
#define HTILES 20
#define WTILES 20
#define DTILES 4

// LDS budget (PRE path): sA 3*14*8*30*2 = 20,160 B; union max(vs 196*32*2,
// sb 3136*4) = 12,544 B; yb 4 B; wsum 16 B => 32,724 B -> rounds to 32,768
// (512B granule, R2 evidence) = exactly 5 blocks/CU (5*32768 = 160 KiB).

struct alignas(8) Half4 { __half x, y, z, w; };

static __device__ __forceinline__ __half2 u2h(unsigned int a) {
    __half2 r; __builtin_memcpy(&r, &a, 4); return r;
}
static __device__ __forceinline__ unsigned int h2u(__half2 v) {
    unsigned int r; __builtin_memcpy(&r, &v, 4); return r;
}
// p = max(v,0) per half; m = (sign clear) ? 1.0h : 0.0h per half.
static __device__ __forceinline__ void pmask(__half2 v, __half2& p, __half2& m) {
    const unsigned int bits = h2u(v);
    const unsigned int neg  = bits & 0x80008000u;
    const unsigned int full = (neg >> 15) * 0xFFFFu;          // 0xFFFF where negative
    p = u2h(bits & ~full);
    m = u2h(((~bits >> 15) & 0x00010001u) * 0x3C00u);         // 1.0h where sign clear
}

__device__ __forceinline__ float sval(float c0, float c1, float c2) {
    // c0=S_m, c1=S_tm, c2=S_t2m over the 343-voxel window; t = m?sigmoid:0.5
    const float S_t  = c1 + 0.5f  * (343.0f - c0);
    const float S_t2 = c2 + 0.25f * (343.0f - c0);
    const float inv  = 1.0f / 343.0f;
    const float ux   = S_t  * inv;
    const float uy   = c0   * inv;
    const float uxx  = S_t2 * inv;
    const float uxy  = c1   * inv;
    const float covn = 49.0f / 48.0f;   // WIN^2/(WIN^2-1)
    const float cc   = 0.00045f;        // (0.03*data_range)^2/2, data_range==1
    const float vx  = covn * (uxx - ux * ux);
    const float vy  = covn * (uy  - uy * uy);
    const float vxy = covn * (uxy - ux * uy);
    return (vxy + cc) * __builtin_amdgcn_rcpf(vx * vy + cc);   // den >= ~3e-4
}

// Pre-pass: v = (y==c ? +sigmoid(x) : -sigmoid(x)) as f16, one value per
// (channel, voxel). Removes the halo-amplified transcendental recompute from
// the main kernel. Also zeroes acc (replaces the hipMemsetAsync dispatch).
__global__ __launch_bounds__(256)
void sigmoid_prepass(const float* __restrict__ x,
                     const int* __restrict__ y,
                     __half* __restrict__ xs,
                     double* __restrict__ acc) {
    if (blockIdx.x == 0 && blockIdx.y == 0 && threadIdx.x == 0) acc[0] = 0.0;
    const int b  = blockIdx.y;
    const int qv = blockIdx.x * 256 + threadIdx.x;    // 0..614399
    const int off = 4 * qv;
    const int4 yv = *(const int4*)(y + (size_t)b * CSTRIDE + off);
#pragma unroll
    for (int c = 0; c < 4; c++) {
        const size_t xo = ((size_t)(b * 4 + c)) * CSTRIDE + off;
        const float4 xv = *(const float4*)(x + xo);
        const float s0 = 1.0f / (1.0f + __expf(-xv.x));
        const float s1 = 1.0f / (1.0f + __expf(-xv.y));
        const float s2 = 1.0f / (1.0f + __expf(-xv.z));
        const float s3 = 1.0f / (1.0f + __expf(-xv.w));
        Half4 hv;
        hv.x = __float2half((yv.x == c) ? s0 : -s0);
        hv.y = __float2half((yv.y == c) ? s1 : -s1);
        hv.z = __float2half((yv.z == c) ? s2 : -s2);
        hv.w = __float2half((yv.w == c) ? s3 : -s3);
        *(Half4*)(xs + xo) = hv;
    }
}

// (256,5): 5 waves/EU target; LDS caps HW occupancy at 5 blocks/CU.
template <bool PRE>
__global__ __launch_bounds__(256, 5)
void structure_loss_main(const float* __restrict__ x,
                         const int* __restrict__ y,
                         const __half* __restrict__ xs,
                         double* __restrict__ acc) {
    // W-window sums, f16 SoA planes [ih][wo][dd]: 3 * 14*8*30*2 = 20,160 B
    __shared__ __half sA0[IH * TW * SAS];
    __shared__ __half sA1[IH * TW * SAS];
    __shared__ __half sA2[IH * TW * SAS];
    // vs (phase 0/A input) and sb (phase B/C) never live together: 12,544 B
    __shared__ union alignas(16) {
        __half  vs[NCOL * IDS];          // staged +/- sigma, f16, lane-linear
        __half2 sb2[64 * SBC + 3];       // H-window sums [col][pair][plane]
    } u;
    __shared__ unsigned int yb[PRE ? 1 : NCOL * 2];   // fallback only
    __shared__ float wsum[4];

    const int dt = blockIdx.x;                 // 0..3
    const int wt = blockIdx.y;                 // 0..19
    const int z  = blockIdx.z;                 // 0..39 = b*HTILES + ht
    const int b  = z / HTILES;
    const int ht = z - b * HTILES;

    const int h0 = ht * TH, w0 = wt * TW;
    const int d0 = dt * TD;                          // output base: 0,24,48,72
    const int dstage = (dt == DTILES - 1) ? 64 : d0; // staged base (16B align)
    const int doff = d0 - dstage;                    // 0 or 8 (uniform)
    const int odmax = min(TD, DOUT - d0);            // 24,24,24,18
    const int* yc = y + (size_t)b * (size_t)CSTRIDE;
    const int t = threadIdx.x;

    if (!PRE) {
        // ---- Phase Y (fallback): stage y tile 2-bit packed, 16 vals/word ----
        for (int i = t; i < NCOL * 2; i += 256) {
            const int col = i >> 1, hf = i & 1;
            const int ih = col / IW, iw = col - ih * IW;
            const int h = min(h0 + ih, H - 1);
            const int w = min(w0 + iw, W - 1);
            const size_t cb = (size_t)(h * W + w) * DD;
            const int dstart = dstage + 16 * hf;     // always in-bounds (<=80)
            unsigned int pk = 0u;
#pragma unroll
            for (int j3 = 0; j3 < 4; j3++) {
                const int4 yv = *(const int4*)(yc + cb + dstart + 4 * j3);
                pk |= (unsigned)(yv.x & 3) << (2 * (4 * j3 + 0));
                pk |= (unsigned)(yv.y & 3) << (2 * (4 * j3 + 1));
                pk |= (unsigned)(yv.z & 3) << (2 * (4 * j3 + 2));
                pk |= (unsigned)(yv.w & 3) << (2 * (4 * j3 + 3));
            }
            yb[i] = pk;
        }
        __syncthreads();
    }

    float lsum = 0.f;

    for (int cl = 0; cl < 4; cl++) {
        if (PRE) {
            // ---- Phase 0 (PRE): Half8 copy of precomputed +/-sigma.
            // 784 items = 196 cols x 4 x uint4; always in-bounds, no padding.
            const __half* xsc = xs + ((size_t)b * 4 + cl) * (size_t)CSTRIDE;
#pragma unroll
            for (int k = 0; k < 4; k++) {
                const int i = t + 256 * k;
                if (i < NCOL * 4) {
                    const int col = i >> 2, q = i & 3;
                    const int ih = col / IW, iw = col - ih * IW;
                    const int h = min(h0 + ih, H - 1);
                    const int w = min(w0 + iw, W - 1);
                    const uint4 vv =
                        *(const uint4*)(xsc + (h * W + w) * DD + dstage + 8 * q);
                    *(uint4*)&u.vs[col * IDS + 8 * q] = vv;
                }
            }
        } else {
            // ---- Phase 0 (fallback): stage x, compute sigmoid, fuse y ----
            const float* xc = x + ((size_t)b * 4 + cl) * (size_t)CSTRIDE;
#pragma unroll
            for (int k = 0; k < 7; k++) {
                const int i = t + 256 * k;
                if (i < NCOL * 8) {
                    const int col = i >> 3, q = i & 7;
                    const int ih = col / IW, iw = col - ih * IW;
                    const int h = min(h0 + ih, H - 1);
                    const int w = min(w0 + iw, W - 1);
                    const int dbase = dstage + 4 * q;   // always in-bounds
                    const float4 xv = *(const float4*)(xc + (h * W + w) * DD + dbase);
                    const unsigned int pk = yb[col * 2 + (q >> 2)] >> (8 * (q & 3));
                    const float s0 = 1.0f / (1.0f + __expf(-xv.x));
                    const float s1 = 1.0f / (1.0f + __expf(-xv.y));
                    const float s2 = 1.0f / (1.0f + __expf(-xv.z));
                    const float s3 = 1.0f / (1.0f + __expf(-xv.w));
                    Half4 hv;
                    hv.x = __float2half(((int)((pk >> 0) & 3u) == cl) ? s0 : -s0);
                    hv.y = __float2half(((int)((pk >> 2) & 3u) == cl) ? s1 : -s1);
                    hv.z = __float2half(((int)((pk >> 4) & 3u) == cl) ? s2 : -s2);
                    hv.w = __float2half(((int)((pk >> 6) & 3u) == cl) ? s3 : -s3);
                    *(Half4*)&u.vs[col * IDS + 4 * q] = hv;
                }
            }
        }
        __syncthreads();

        // ---- Phase A: W-window, packed f16 over dd-pairs. 210 items (ih,dp).
        // Window dd = staged[doff + dd]; dp >= 12 at dt==3 clamps to staged
        // end (real finite data) and feeds only od >= 18 outputs, which the
        // odmax guard discards.
        if (t < IH * NDP) {
            const int ih = t / NDP, dp = t - ih * NDP;
            const int s  = min(doff + 2 * dp, IDS - 2);
            const __half2 z2 = __float2half2_rn(0.f);
            __half2 v2[IW];
            const int vbase = ih * IW * IDS + s;
#pragma unroll
            for (int iw = 0; iw < IW; iw++)
                v2[iw] = *(const __half2*)&u.vs[vbase + iw * IDS];
            __half2 sm = z2, sp = z2, sq = z2;
#pragma unroll
            for (int iw = 0; iw < WINS; iw++) {
                __half2 p, m;
                pmask(v2[iw], p, m);
                sm = __hadd2(sm, m);
                sp = __hadd2(sp, p);
                sq = __hfma2(p, v2[iw], sq);
            }
            int o = (ih * TW) * SAS + 2 * dp;
            *(__half2*)&sA0[o] = sm;
            *(__half2*)&sA1[o] = sp;
            *(__half2*)&sA2[o] = sq;
#pragma unroll
            for (int wo = 1; wo < TW; wo++) {
                const __half2 a = v2[wo + 6], bb = v2[wo - 1];
                __half2 pa, ma, pb, mb;
                pmask(a, pa, ma);
                pmask(bb, pb, mb);
                sm = __hadd2(sm, __hsub2(ma, mb));
                sp = __hadd2(sp, __hsub2(pa, pb));
                sq = __hadd2(sq, __hsub2(__hmul2(pa, a), __hmul2(pb, bb)));
                o += SAS;
                *(__half2*)&sA0[o] = sm;
                *(__half2*)&sA1[o] = sp;
                *(__half2*)&sA2[o] = sq;
            }
        }
        __syncthreads();   // sA ready; vs reads retired before sb overwrites union

        // ---- Phase B: H-window, packed f16 over dd-pairs. 240 items ----
        if (t < 2 * TW * NDP) {
            const int dp = t % NDP;
            const int r  = t / NDP;
            const int wo = r & 7;
            const int ho0 = (r >> 3) * 4;          // 0 or 4
            __half2 a0[10], a1[10], a2[10];
#pragma unroll
            for (int k = 0; k < 10; k++) {
                const int idx = ((ho0 + k) * TW + wo) * SAS + 2 * dp;
                a0[k] = *(const __half2*)&sA0[idx];
                a1[k] = *(const __half2*)&sA1[idx];
                a2[k] = *(const __half2*)&sA2[idx];
            }
            __half2 s0 = a0[0], s1 = a1[0], s2 = a2[0];
#pragma unroll
            for (int k = 1; k < WINS; k++) {
                s0 = __hadd2(s0, a0[k]);
                s1 = __hadd2(s1, a1[k]);
                s2 = __hadd2(s2, a2[k]);
            }
            int o = ((ho0 * TW + wo) * SBC) + dp * 3;
            u.sb2[o] = s0; u.sb2[o + 1] = s1; u.sb2[o + 2] = s2;
#pragma unroll
            for (int k = 1; k < 4; k++) {
                s0 = __hadd2(s0, __hsub2(a0[k + 6], a0[k - 1]));
                s1 = __hadd2(s1, __hsub2(a1[k + 6], a1[k - 1]));
                s2 = __hadd2(s2, __hsub2(a2[k + 6], a2[k - 1]));
                o += TW * SBC;
                u.sb2[o] = s0; u.sb2[o + 1] = s1; u.sb2[o + 2] = s2;
            }
        }
        __syncthreads();

        // ---- Phase C: D-window, slide 6 outputs. Full 256 threads (ho,wo,dq).
        {
            const int dq = t & 3;                  // pairs 3dq..3dq+5
            const int wo = (t >> 2) & 7;
            const int ho = t >> 5;
            const int hg = h0 + ho, wg = w0 + wo;
            if (hg < HO && wg < WO) {
                const int base2 = (ho * TW + wo) * SBC + 9 * dq;
                float b0[12], b1[12], b2[12];
#pragma unroll
                for (int k = 0; k < 6; k++) {
                    float2 f;
                    f = __half22float2(u.sb2[base2 + 3 * k + 0]);
                    b0[2 * k] = f.x; b0[2 * k + 1] = f.y;
                    f = __half22float2(u.sb2[base2 + 3 * k + 1]);
                    b1[2 * k] = f.x; b1[2 * k + 1] = f.y;
                    f = __half22float2(u.sb2[base2 + 3 * k + 2]);
                    b2[2 * k] = f.x; b2[2 * k + 1] = f.y;
                }
                float s0 = 0.f, s1 = 0.f, s2 = 0.f;
#pragma unroll
                for (int k = 0; k < WINS; k++) { s0 += b0[k]; s1 += b1[k]; s2 += b2[k]; }
                const int od0 = 6 * dq;
#pragma unroll
                for (int k = 0; k < 6; k++) {
                    if (k > 0) {
                        s0 += b0[k + 6] - b0[k - 1];
                        s1 += b1[k + 6] - b1[k - 1];
                        s2 += b2[k + 6] - b2[k - 1];
                    }
                    if (od0 + k < odmax) lsum += sval(s0, s1, s2);
                }
            }
        }
        __syncthreads();   // retire sb reads before next class overwrites union
    }

    // wave(64) shuffle reduce, then cross-wave via LDS, one atomic per block
#pragma unroll
    for (int off = 32; off > 0; off >>= 1) lsum += __shfl_down(lsum, off, 64);
    const int wave = t >> 6;
    if ((t & 63) == 0) wsum[wave] = lsum;
    __syncthreads();
    if (t == 0) {
        const float s = wsum[0] + wsum[1] + wsum[2] + wsum[3];
        atomicAdd(acc, (double)s);
    }
}

__global__ void structure_loss_finalize(const double* __restrict__ acc,
                                        float* __restrict__ out) {
    out[0] = 1.0f - (float)(acc[0] / 17075520.0);   // 8*154*154*90
}

extern "C" void kernel_launch(void* const* d_in, const int* in_sizes, int n_in,
                              void* d_out, int out_size, void* d_ws, size_t ws_size,
                              hipStream_t stream) {
    const float* x = (const float*)d_in[0];
    const int*   y = (const int*)d_in[1];
    double* acc = (double*)d_ws;
    __half* xs = (__half*)((char*)d_ws + 16);

    const size_t need = 16 + (size_t)8 * CSTRIDE * sizeof(__half);   // ~39.3 MB
    dim3 grid(DTILES, WTILES, 2 * HTILES);   // (4, 20, 40) = 3,200 blocks

    if (ws_size >= need) {
        // prepass zeroes acc -> 3 dispatches total
        sigmoid_prepass<<<dim3(2400, 2), 256, 0, stream>>>(x, y, xs, acc);
        structure_loss_main<true><<<grid, 256, 0, stream>>>(x, y, xs, acc);
    } else {
        (void)hipMemsetAsync(d_ws, 0, sizeof(double), stream);
        structure_loss_main<false><<<grid, 256, 0, stream>>>(x, y, xs, acc);
    }
    structure_loss_finalize<<<1, 1, 0, stream>>>(acc, (float*)d_out);
}

// Round 4
// 196.762 us; speedup vs baseline: 1.6496x; 1.0128x over previous
//
#include <hip/hip_runtime.h>
#include <hip/hip_fp16.h>

// Problem geometry (fixed by reference)
#define WINS 7
#define H 160
#define W 160
#define DD 96
#define HO 154          // H - WINS + 1
#define WO 154
#define DOUT 90
#define CSTRIDE (H*W*DD)   // per-(b,c) channel stride

// Tile: 8x8x24 outputs, all 4 classes sequentially per block.
#define TH 8
#define TW 8
#define TD 24
#define IH 14            // TH + WINS - 1
#define IW 14
#define NCOL (IH * IW)   // 196
#define IDS 32           // staged halfs per column (4 x uint4, 16B aligned)
#define IDW 30           // window extent used = TD + WINS - 1
#define NDP 15           // dd-pairs per column
#define SAS 30           // sA row stride in halfs
#define SBC 49           // sb col stride in half2 units
#define HTILES 20
#define WTILES 20
#define DTILES 4

// vs swizzle: columns live in 128B pairs (cols 2k,2k+1 -- always same ih row
// since rows start at even col 14*ih). 16B chunk index within pair
// cp = ((col&1)<<2)|q is XORed with g(ih) = ((ih&1)<<2)|((ih>>1)&3).
//  - Phase-0 ds_write_b128: each 8-lane phase = one pair; cp^g bijective on
//    0..7 -> all 32 banks -> stays conflict-free.
//  - Phase-A fixed-iw read: old bank = (dp + 16(iw&1))%32, ih-invariant
//    (ih stride 896B == 0 mod 128) -> 4.3-way on EVERY read = the 7.3M
//    SQ_LDS_BANK_CONFLICT (unchanged across R0-R2 sA/sb relayouts; only
//    moved when vs stride changed in R3). g(ih) spreads ih over both
//    16-bank halves -> <=3-way on ~3 banks, 2-way (free) elsewhere.
//  - Reads stay affine: even-iw chain at base, odd-iw at base^64, stride 128.

// LDS budget (PRE): sA 20,160 + union 12,544 + wsum 16 + yb 4 = 32,724
// -> rounds to 32,768 = exactly 5 blocks/CU.

struct alignas(8) Half4 { __half x, y, z, w; };

static __device__ __forceinline__ __half2 u2h(unsigned int a) {
    __half2 r; __builtin_memcpy(&r, &a, 4); return r;
}
static __device__ __forceinline__ unsigned int h2u(__half2 v) {
    unsigned int r; __builtin_memcpy(&r, &v, 4); return r;
}
// p = max(v,0) per half; m = (sign clear) ? 1.0h : 0.0h per half.
static __device__ __forceinline__ void pmask(__half2 v, __half2& p, __half2& m) {
    const unsigned int bits = h2u(v);
    const unsigned int neg  = bits & 0x80008000u;
    const unsigned int full = (neg >> 15) * 0xFFFFu;          // 0xFFFF where negative
    p = u2h(bits & ~full);
    m = u2h(((~bits >> 15) & 0x00010001u) * 0x3C00u);         // 1.0h where sign clear
}

__device__ __forceinline__ float sval(float c0, float c1, float c2) {
    // c0=S_m, c1=S_tm, c2=S_t2m over the 343-voxel window; t = m?sigmoid:0.5
    const float S_t  = c1 + 0.5f  * (343.0f - c0);
    const float S_t2 = c2 + 0.25f * (343.0f - c0);
    const float inv  = 1.0f / 343.0f;
    const float ux   = S_t  * inv;
    const float uy   = c0   * inv;
    const float uxx  = S_t2 * inv;
    const float uxy  = c1   * inv;
    const float covn = 49.0f / 48.0f;   // WIN^2/(WIN^2-1)
    const float cc   = 0.00045f;        // (0.03*data_range)^2/2, data_range==1
    const float vx  = covn * (uxx - ux * ux);
    const float vy  = covn * (uy  - uy * uy);
    const float vxy = covn * (uxy - ux * uy);
    return (vxy + cc) * __builtin_amdgcn_rcpf(vx * vy + cc);   // den >= ~3e-4
}

// Pre-pass: v = (y==c ? +sigmoid(x) : -sigmoid(x)) as f16, one value per
// (channel, voxel). Also zeroes acc (replaces the hipMemsetAsync dispatch).
__global__ __launch_bounds__(256)
void sigmoid_prepass(const float* __restrict__ x,
                     const int* __restrict__ y,
                     __half* __restrict__ xs,
                     double* __restrict__ acc) {
    if (blockIdx.x == 0 && blockIdx.y == 0 && threadIdx.x == 0) acc[0] = 0.0;
    const int b  = blockIdx.y;
    const int qv = blockIdx.x * 256 + threadIdx.x;    // 0..614399
    const int off = 4 * qv;
    const int4 yv = *(const int4*)(y + (size_t)b * CSTRIDE + off);
#pragma unroll
    for (int c = 0; c < 4; c++) {
        const size_t xo = ((size_t)(b * 4 + c)) * CSTRIDE + off;
        const float4 xv = *(const float4*)(x + xo);
        const float s0 = 1.0f / (1.0f + __expf(-xv.x));
        const float s1 = 1.0f / (1.0f + __expf(-xv.y));
        const float s2 = 1.0f / (1.0f + __expf(-xv.z));
        const float s3 = 1.0f / (1.0f + __expf(-xv.w));
        Half4 hv;
        hv.x = __float2half((yv.x == c) ? s0 : -s0);
        hv.y = __float2half((yv.y == c) ? s1 : -s1);
        hv.z = __float2half((yv.z == c) ? s2 : -s2);
        hv.w = __float2half((yv.w == c) ? s3 : -s3);
        *(Half4*)(xs + xo) = hv;
    }
}

// (256,5): 5 waves/EU target; LDS caps HW occupancy at 5 blocks/CU.
template <bool PRE>
__global__ __launch_bounds__(256, 5)
void structure_loss_main(const float* __restrict__ x,
                         const int* __restrict__ y,
                         const __half* __restrict__ xs,
                         double* __restrict__ acc) {
    // W-window sums, f16 SoA planes [ih][wo][dd]: 3 * 14*8*30*2 = 20,160 B
    __shared__ __half sA0[IH * TW * SAS];
    __shared__ __half sA1[IH * TW * SAS];
    __shared__ __half sA2[IH * TW * SAS];
    // vs (phase 0/A input) and sb (phase B/C) never live together: 12,544 B
    __shared__ union alignas(16) {
        __half  vs[NCOL * IDS];          // staged +/- sigma, f16, pair-swizzled
        __half2 sb2[64 * SBC + 3];       // H-window sums [col][pair][plane]
    } u;
    __shared__ unsigned int yb[PRE ? 1 : NCOL * 2];   // fallback only
    __shared__ float wsum[4];

    const int dt = blockIdx.x;                 // 0..3
    const int wt = blockIdx.y;                 // 0..19
    const int z  = blockIdx.z;                 // 0..39 = b*HTILES + ht
    const int b  = z / HTILES;
    const int ht = z - b * HTILES;

    const int h0 = ht * TH, w0 = wt * TW;
    const int d0 = dt * TD;                          // output base: 0,24,48,72
    const int dstage = (dt == DTILES - 1) ? 64 : d0; // staged base (16B align)
    const int doff = d0 - dstage;                    // 0 or 8 (uniform)
    const int odmax = min(TD, DOUT - d0);            // 24,24,24,18
    const int* yc = y + (size_t)b * (size_t)CSTRIDE;
    const int t = threadIdx.x;

    if (!PRE) {
        // ---- Phase Y (fallback): stage y tile 2-bit packed, 16 vals/word ----
        for (int i = t; i < NCOL * 2; i += 256) {
            const int col = i >> 1, hf = i & 1;
            const int ih = col / IW, iw = col - ih * IW;
            const int h = min(h0 + ih, H - 1);
            const int w = min(w0 + iw, W - 1);
            const size_t cb = (size_t)(h * W + w) * DD;
            const int dstart = dstage + 16 * hf;     // always in-bounds (<=80)
            unsigned int pk = 0u;
#pragma unroll
            for (int j3 = 0; j3 < 4; j3++) {
                const int4 yv = *(const int4*)(yc + cb + dstart + 4 * j3);
                pk |= (unsigned)(yv.x & 3) << (2 * (4 * j3 + 0));
                pk |= (unsigned)(yv.y & 3) << (2 * (4 * j3 + 1));
                pk |= (unsigned)(yv.z & 3) << (2 * (4 * j3 + 2));
                pk |= (unsigned)(yv.w & 3) << (2 * (4 * j3 + 3));
            }
            yb[i] = pk;
        }
        __syncthreads();
    }

    float lsum = 0.f;

    for (int cl = 0; cl < 4; cl++) {
        if (PRE) {
            // ---- Phase 0 (PRE): Half8 copy of precomputed +/-sigma into the
            // pair-swizzled vs. 784 items = 196 cols x 4 x uint4.
            const __half* xsc = xs + ((size_t)b * 4 + cl) * (size_t)CSTRIDE;
#pragma unroll
            for (int k = 0; k < 4; k++) {
                const int i = t + 256 * k;
                if (i < NCOL * 4) {
                    const int col = i >> 2, q = i & 3;
                    const int ih = col / IW, iw = col - ih * IW;
                    const int h = min(h0 + ih, H - 1);
                    const int w = min(w0 + iw, W - 1);
                    const uint4 vv =
                        *(const uint4*)(xsc + (h * W + w) * DD + dstage + 8 * q);
                    const int g  = ((ih & 1) << 2) | ((ih >> 1) & 3);
                    const int cp = ((col & 1) << 2) | q;       // col&1 == iw&1
                    const int lofs = ((col >> 1) << 7) | ((cp ^ g) << 4);
                    *(uint4*)((char*)u.vs + lofs) = vv;
                }
            }
        } else {
            // ---- Phase 0 (fallback): stage x, compute sigmoid, fuse y ----
            const float* xc = x + ((size_t)b * 4 + cl) * (size_t)CSTRIDE;
#pragma unroll
            for (int k = 0; k < 7; k++) {
                const int i = t + 256 * k;
                if (i < NCOL * 8) {
                    const int col = i >> 3, q = i & 7;
                    const int ih = col / IW, iw = col - ih * IW;
                    const int h = min(h0 + ih, H - 1);
                    const int w = min(w0 + iw, W - 1);
                    const int dbase = dstage + 4 * q;   // always in-bounds
                    const float4 xv = *(const float4*)(xc + (h * W + w) * DD + dbase);
                    const unsigned int pk = yb[col * 2 + (q >> 2)] >> (8 * (q & 3));
                    const float s0 = 1.0f / (1.0f + __expf(-xv.x));
                    const float s1 = 1.0f / (1.0f + __expf(-xv.y));
                    const float s2 = 1.0f / (1.0f + __expf(-xv.z));
                    const float s3 = 1.0f / (1.0f + __expf(-xv.w));
                    Half4 hv;
                    hv.x = __float2half(((int)((pk >> 0) & 3u) == cl) ? s0 : -s0);
                    hv.y = __float2half(((int)((pk >> 2) & 3u) == cl) ? s1 : -s1);
                    hv.z = __float2half(((int)((pk >> 4) & 3u) == cl) ? s2 : -s2);
                    hv.w = __float2half(((int)((pk >> 6) & 3u) == cl) ? s3 : -s3);
                    const int g  = ((ih & 1) << 2) | ((ih >> 1) & 3);
                    const int cp = ((col & 1) << 2) | (q >> 1);
                    const int lofs = ((col >> 1) << 7) | ((cp ^ g) << 4) | ((q & 1) << 3);
                    *(Half4*)((char*)u.vs + lofs) = hv;
                }
            }
        }
        __syncthreads();

        // ---- Phase A: W-window, packed f16 over dd-pairs. 210 items (ih,dp).
        // Swizzled read: even-iw chain at base_e, odd-iw at base_e^64, both
        // stride 128 (pair stride). half2 at (2s&15) never straddles a chunk
        // (s even). dp >= 12 at dt==3 clamps to staged end; feeds only
        // od >= 18 outputs, discarded by the odmax guard.
        if (t < IH * NDP) {
            const int ih = t / NDP, dp = t - ih * NDP;
            const int s  = min(doff + 2 * dp, IDS - 2);
            const int g  = ((ih & 1) << 2) | ((ih >> 1) & 3);
            const int c0 = s >> 3;
            const int base_e = ih * (7 * 128) + ((c0 ^ g) << 4) + ((2 * s) & 15);
            const __half2 z2 = __float2half2_rn(0.f);
            __half2 v2[IW];
#pragma unroll
            for (int iw = 0; iw < IW; iw++) {
                const int ad = ((iw & 1) ? (base_e ^ 64) : base_e) + (iw >> 1) * 128;
                v2[iw] = *(const __half2*)((const char*)u.vs + ad);
            }
            __half2 sm = z2, sp = z2, sq = z2;
#pragma unroll
            for (int iw = 0; iw < WINS; iw++) {
                __half2 p, m;
                pmask(v2[iw], p, m);
                sm = __hadd2(sm, m);
                sp = __hadd2(sp, p);
                sq = __hfma2(p, v2[iw], sq);
            }
            int o = (ih * TW) * SAS + 2 * dp;
            *(__half2*)&sA0[o] = sm;
            *(__half2*)&sA1[o] = sp;
            *(__half2*)&sA2[o] = sq;
#pragma unroll
            for (int wo = 1; wo < TW; wo++) {
                const __half2 a = v2[wo + 6], bb = v2[wo - 1];
                __half2 pa, ma, pb, mb;
                pmask(a, pa, ma);
                pmask(bb, pb, mb);
                sm = __hadd2(sm, __hsub2(ma, mb));
                sp = __hadd2(sp, __hsub2(pa, pb));
                sq = __hadd2(sq, __hsub2(__hmul2(pa, a), __hmul2(pb, bb)));
                o += SAS;
                *(__half2*)&sA0[o] = sm;
                *(__half2*)&sA1[o] = sp;
                *(__half2*)&sA2[o] = sq;
            }
        }
        __syncthreads();   // sA ready; vs reads retired before sb overwrites union

        // ---- Phase B: H-window, packed f16 over dd-pairs. 240 items ----
        if (t < 2 * TW * NDP) {
            const int dp = t % NDP;
            const int r  = t / NDP;
            const int wo = r & 7;
            const int ho0 = (r >> 3) * 4;          // 0 or 4
            __half2 a0[10], a1[10], a2[10];
#pragma unroll
            for (int k = 0; k < 10; k++) {
                const int idx = ((ho0 + k) * TW + wo) * SAS + 2 * dp;
                a0[k] = *(const __half2*)&sA0[idx];
                a1[k] = *(const __half2*)&sA1[idx];
                a2[k] = *(const __half2*)&sA2[idx];
            }
            __half2 s0 = a0[0], s1 = a1[0], s2 = a2[0];
#pragma unroll
            for (int k = 1; k < WINS; k++) {
                s0 = __hadd2(s0, a0[k]);
                s1 = __hadd2(s1, a1[k]);
                s2 = __hadd2(s2, a2[k]);
            }
            int o = ((ho0 * TW + wo) * SBC) + dp * 3;
            u.sb2[o] = s0; u.sb2[o + 1] = s1; u.sb2[o + 2] = s2;
#pragma unroll
            for (int k = 1; k < 4; k++) {
                s0 = __hadd2(s0, __hsub2(a0[k + 6], a0[k - 1]));
                s1 = __hadd2(s1, __hsub2(a1[k + 6], a1[k - 1]));
                s2 = __hadd2(s2, __hsub2(a2[k + 6], a2[k - 1]));
                o += TW * SBC;
                u.sb2[o] = s0; u.sb2[o + 1] = s1; u.sb2[o + 2] = s2;
            }
        }
        __syncthreads();

        // ---- Phase C: D-window, slide 6 outputs. Full 256 threads (ho,wo,dq).
        {
            const int dq = t & 3;                  // pairs 3dq..3dq+5
            const int wo = (t >> 2) & 7;
            const int ho = t >> 5;
            const int hg = h0 + ho, wg = w0 + wo;
            if (hg < HO && wg < WO) {
                const int base2 = (ho * TW + wo) * SBC + 9 * dq;
                float b0[12], b1[12], b2[12];
#pragma unroll
                for (int k = 0; k < 6; k++) {
                    float2 f;
                    f = __half22float2(u.sb2[base2 + 3 * k + 0]);
                    b0[2 * k] = f.x; b0[2 * k + 1] = f.y;
                    f = __half22float2(u.sb2[base2 + 3 * k + 1]);
                    b1[2 * k] = f.x; b1[2 * k + 1] = f.y;
                    f = __half22float2(u.sb2[base2 + 3 * k + 2]);
                    b2[2 * k] = f.x; b2[2 * k + 1] = f.y;
                }
                float s0 = 0.f, s1 = 0.f, s2 = 0.f;
#pragma unroll
                for (int k = 0; k < WINS; k++) { s0 += b0[k]; s1 += b1[k]; s2 += b2[k]; }
                const int od0 = 6 * dq;
#pragma unroll
                for (int k = 0; k < 6; k++) {
                    if (k > 0) {
                        s0 += b0[k + 6] - b0[k - 1];
                        s1 += b1[k + 6] - b1[k - 1];
                        s2 += b2[k + 6] - b2[k - 1];
                    }
                    if (od0 + k < odmax) lsum += sval(s0, s1, s2);
                }
            }
        }
        __syncthreads();   // retire sb reads before next class overwrites union
    }

    // wave(64) shuffle reduce, then cross-wave via LDS, one atomic per block
#pragma unroll
    for (int off = 32; off > 0; off >>= 1) lsum += __shfl_down(lsum, off, 64);
    const int wave = t >> 6;
    if ((t & 63) == 0) wsum[wave] = lsum;
    __syncthreads();
    if (t == 0) {
        const float s = wsum[0] + wsum[1] + wsum[2] + wsum[3];
        atomicAdd(acc, (double)s);
    }
}

__global__ void structure_loss_finalize(const double* __restrict__ acc,
                                        float* __restrict__ out) {
    out[0] = 1.0f - (float)(acc[0] / 17075520.0);   // 8*154*154*90
}

extern "C" void kernel_launch(void* const* d_in, const int* in_sizes, int n_in,
                              void* d_out, int out_size, void* d_ws, size_t ws_size,
                              hipStream_t stream) {
    const float* x = (const float*)d_in[0];
    const int*   y = (const int*)d_in[1];
    double* acc = (double*)d_ws;
    __half* xs = (__half*)((char*)d_ws + 16);

    const size_t need = 16 + (size_t)8 * CSTRIDE * sizeof(__half);   // ~39.3 MB
    dim3 grid(DTILES, WTILES, 2 * HTILES);   // (4, 20, 40) = 3,200 blocks

    if (ws_size >= need) {
        // prepass zeroes acc -> 3 dispatches total
        sigmoid_prepass<<<dim3(2400, 2), 256, 0, stream>>>(x, y, xs, acc);
        structure_loss_main<true><<<grid, 256, 0, stream>>>(x, y, xs, acc);
    } else {
        (void)hipMemsetAsync(d_ws, 0, sizeof(double), stream);
        structure_loss_main<false><<<grid, 256, 0, stream>>>(x, y, xs, acc);
    }
    structure_loss_finalize<<<1, 1, 0, stream>>>(acc, (float*)d_out);
}

// Round 5
// 187.112 us; speedup vs baseline: 1.7346x; 1.0516x over previous
//
#include <hip/hip_runtime.h>
#include <hip/hip_fp16.h>

// Problem geometry (fixed by reference)
#define WINS 7
#define H 160
#define W 160
#define DD 96
#define HO 154          // H - WINS + 1
#define WO 154
#define DOUT 90
#define CSTRIDE (H*W*DD)   // per-(b,c) channel stride

// Tile: 8x8x24 outputs, all 4 classes sequentially per block.
#define TH 8
#define TW 8
#define TD 24
#define IH 14            // TH + WINS - 1
#define IW 14
#define NCOL (IH * IW)   // 196
#define IDS 32           // staged halfs per column (4 x uint4, 16B aligned)
#define IDW 30           // window extent used = TD + WINS - 1
#define NDP 15           // dd-pairs per column
#define SAS 30           // sA row stride in halfs
#define SBC 49           // sb col stride in half2 units
#define HTILES 20
#define WTILES 20
#define DTILES 4

// vs swizzle (R4, kept): 16B chunk cp = ((col&1)<<2)|q XOR g(ih) =
// ((ih&1)<<2)|((ih>>1)&3) within 128B column-pairs. Write stays
// conflict-free; Phase-A read conflicts 7.3M -> 6.0M.
//
// R5: T14 async-stage split. Staging loads for class cl+1 are issued into
// registers right after class cl's vs ds_write (they depend on nothing in
// LDS); the ds_write into the vs/sb union waits for Phase C's barrier as
// before. Removes the per-class {issue loads -> syncthreads -> full
// HBM/L3 latency} stall (FETCH=123MB says staging mostly misses L2).
// Per-thread staging offsets + all class-invariant phase index math
// (divides by 14/15) hoisted out of the class loop.

// LDS budget (PRE): sA 20,160 + union 12,544 + wsum 16 + yb 4 = 32,724
// -> rounds to 32,768 = exactly 5 blocks/CU.

struct alignas(8) Half4 { __half x, y, z, w; };

static __device__ __forceinline__ __half2 u2h(unsigned int a) {
    __half2 r; __builtin_memcpy(&r, &a, 4); return r;
}
static __device__ __forceinline__ unsigned int h2u(__half2 v) {
    unsigned int r; __builtin_memcpy(&r, &v, 4); return r;
}
// p = max(v,0) per half; m = (sign clear) ? 1.0h : 0.0h per half.
static __device__ __forceinline__ void pmask(__half2 v, __half2& p, __half2& m) {
    const unsigned int bits = h2u(v);
    const unsigned int neg  = bits & 0x80008000u;
    const unsigned int full = (neg >> 15) * 0xFFFFu;          // 0xFFFF where negative
    p = u2h(bits & ~full);
    m = u2h(((~bits >> 15) & 0x00010001u) * 0x3C00u);         // 1.0h where sign clear
}

__device__ __forceinline__ float sval(float c0, float c1, float c2) {
    // c0=S_m, c1=S_tm, c2=S_t2m over the 343-voxel window; t = m?sigmoid:0.5
    const float S_t  = c1 + 0.5f  * (343.0f - c0);
    const float S_t2 = c2 + 0.25f * (343.0f - c0);
    const float inv  = 1.0f / 343.0f;
    const float ux   = S_t  * inv;
    const float uy   = c0   * inv;
    const float uxx  = S_t2 * inv;
    const float uxy  = c1   * inv;
    const float covn = 49.0f / 48.0f;   // WIN^2/(WIN^2-1)
    const float cc   = 0.00045f;        // (0.03*data_range)^2/2, data_range==1
    const float vx  = covn * (uxx - ux * ux);
    const float vy  = covn * (uy  - uy * uy);
    const float vxy = covn * (uxy - ux * uy);
    return (vxy + cc) * __builtin_amdgcn_rcpf(vx * vy + cc);   // den >= ~3e-4
}

// Pre-pass: v = (y==c ? +sigmoid(x) : -sigmoid(x)) as f16, one value per
// (channel, voxel). Also zeroes acc (replaces the hipMemsetAsync dispatch).
__global__ __launch_bounds__(256)
void sigmoid_prepass(const float* __restrict__ x,
                     const int* __restrict__ y,
                     __half* __restrict__ xs,
                     double* __restrict__ acc) {
    if (blockIdx.x == 0 && blockIdx.y == 0 && threadIdx.x == 0) acc[0] = 0.0;
    const int b  = blockIdx.y;
    const int qv = blockIdx.x * 256 + threadIdx.x;    // 0..614399
    const int off = 4 * qv;
    const int4 yv = *(const int4*)(y + (size_t)b * CSTRIDE + off);
#pragma unroll
    for (int c = 0; c < 4; c++) {
        const size_t xo = ((size_t)(b * 4 + c)) * CSTRIDE + off;
        const float4 xv = *(const float4*)(x + xo);
        const float s0 = 1.0f / (1.0f + __expf(-xv.x));
        const float s1 = 1.0f / (1.0f + __expf(-xv.y));
        const float s2 = 1.0f / (1.0f + __expf(-xv.z));
        const float s3 = 1.0f / (1.0f + __expf(-xv.w));
        Half4 hv;
        hv.x = __float2half((yv.x == c) ? s0 : -s0);
        hv.y = __float2half((yv.y == c) ? s1 : -s1);
        hv.z = __float2half((yv.z == c) ? s2 : -s2);
        hv.w = __float2half((yv.w == c) ? s3 : -s3);
        *(Half4*)(xs + xo) = hv;
    }
}

// (256,5): 5 waves/EU target; LDS caps HW occupancy at 5 blocks/CU.
template <bool PRE>
__global__ __launch_bounds__(256, 5)
void structure_loss_main(const float* __restrict__ x,
                         const int* __restrict__ y,
                         const __half* __restrict__ xs,
                         double* __restrict__ acc) {
    // W-window sums, f16 SoA planes [ih][wo][dd]: 3 * 14*8*30*2 = 20,160 B
    __shared__ __half sA0[IH * TW * SAS];
    __shared__ __half sA1[IH * TW * SAS];
    __shared__ __half sA2[IH * TW * SAS];
    // vs (phase 0/A input) and sb (phase B/C) never live together: 12,544 B
    __shared__ union alignas(16) {
        __half  vs[NCOL * IDS];          // staged +/- sigma, f16, pair-swizzled
        __half2 sb2[64 * SBC + 3];       // H-window sums [col][pair][plane]
    } u;
    __shared__ unsigned int yb[PRE ? 1 : NCOL * 2];   // fallback only
    __shared__ float wsum[4];

    const int dt = blockIdx.x;                 // 0..3
    const int wt = blockIdx.y;                 // 0..19
    const int z  = blockIdx.z;                 // 0..39 = b*HTILES + ht
    const int b  = z / HTILES;
    const int ht = z - b * HTILES;

    const int h0 = ht * TH, w0 = wt * TW;
    const int d0 = dt * TD;                          // output base: 0,24,48,72
    const int dstage = (dt == DTILES - 1) ? 64 : d0; // staged base (16B align)
    const int doff = d0 - dstage;                    // 0 or 8 (uniform)
    const int odmax = min(TD, DOUT - d0);            // 24,24,24,18
    const int* yc = y + (size_t)b * (size_t)CSTRIDE;
    const int t = threadIdx.x;

    // ---- Hoisted per-thread staging descriptors + class-0 prefetch (PRE) ----
    int gof0, gof1, gof2, gof3 = -1;
    int lof0, lof1, lof2, lof3 = 0;
    uint4 pf0, pf1, pf2, pf3;
    if (PRE) {
#pragma unroll
        for (int k = 0; k < 4; k++) {
            const int i = t + 256 * k;
            if (i < NCOL * 4) {
                const int col = i >> 2, q = i & 3;
                const int ih = col / IW, iw = col - ih * IW;
                const int h = min(h0 + ih, H - 1);
                const int w = min(w0 + iw, W - 1);
                const int go = (h * W + w) * DD + dstage + 8 * q;
                const int g  = ((ih & 1) << 2) | ((ih >> 1) & 3);
                const int cp = ((col & 1) << 2) | q;
                const int lo = ((col >> 1) << 7) | ((cp ^ g) << 4);
                if (k == 0) { gof0 = go; lof0 = lo; }
                else if (k == 1) { gof1 = go; lof1 = lo; }
                else if (k == 2) { gof2 = go; lof2 = lo; }
                else { gof3 = go; lof3 = lo; }
            }
        }
        const __half* xsc0 = xs + ((size_t)b * 4) * (size_t)CSTRIDE;
        pf0 = *(const uint4*)(xsc0 + gof0);
        pf1 = *(const uint4*)(xsc0 + gof1);
        pf2 = *(const uint4*)(xsc0 + gof2);
        if (gof3 >= 0) pf3 = *(const uint4*)(xsc0 + gof3);
    }

    // ---- Hoisted class-invariant phase index math ----
    // Phase A (210 items):
    const bool  actA = (t < IH * NDP);
    const int   ihA  = t / NDP, dpA = t - ihA * NDP;
    const int   sA_  = min(doff + 2 * dpA, IDS - 2);
    const int   gA   = ((ihA & 1) << 2) | ((ihA >> 1) & 3);
    const int   baseE = ihA * (7 * 128) + (((sA_ >> 3) ^ gA) << 4) + ((2 * sA_) & 15);
    const int   oA0  = (ihA * TW) * SAS + 2 * dpA;
    // Phase B (240 items):
    const bool  actB = (t < 2 * TW * NDP);
    const int   rB   = t / NDP, dpB = t - rB * NDP;
    const int   woB  = rB & 7, ho0B = (rB >> 3) * 4;
    const int   idxB0 = (ho0B * TW + woB) * SAS + 2 * dpB;
    const int   oB0  = ((ho0B * TW + woB) * SBC) + dpB * 3;
    // Phase C:
    const int   dqC  = t & 3, woC = (t >> 2) & 7, hoC = t >> 5;
    const bool  actC = (h0 + hoC < HO) && (w0 + woC < WO);
    const int   base2C = (hoC * TW + woC) * SBC + 9 * dqC;

    if (!PRE) {
        // ---- Phase Y (fallback): stage y tile 2-bit packed, 16 vals/word ----
        for (int i = t; i < NCOL * 2; i += 256) {
            const int col = i >> 1, hf = i & 1;
            const int ih = col / IW, iw = col - ih * IW;
            const int h = min(h0 + ih, H - 1);
            const int w = min(w0 + iw, W - 1);
            const size_t cb = (size_t)(h * W + w) * DD;
            const int dstart = dstage + 16 * hf;     // always in-bounds (<=80)
            unsigned int pk = 0u;
#pragma unroll
            for (int j3 = 0; j3 < 4; j3++) {
                const int4 yv = *(const int4*)(yc + cb + dstart + 4 * j3);
                pk |= (unsigned)(yv.x & 3) << (2 * (4 * j3 + 0));
                pk |= (unsigned)(yv.y & 3) << (2 * (4 * j3 + 1));
                pk |= (unsigned)(yv.z & 3) << (2 * (4 * j3 + 2));
                pk |= (unsigned)(yv.w & 3) << (2 * (4 * j3 + 3));
            }
            yb[i] = pk;
        }
        __syncthreads();
    }

    float lsum = 0.f;

    for (int cl = 0; cl < 4; cl++) {
        if (PRE) {
            // ---- Phase 0 (PRE): spill prefetched regs into swizzled vs ----
            *(uint4*)((char*)u.vs + lof0) = pf0;
            *(uint4*)((char*)u.vs + lof1) = pf1;
            *(uint4*)((char*)u.vs + lof2) = pf2;
            if (gof3 >= 0) *(uint4*)((char*)u.vs + lof3) = pf3;
        } else {
            // ---- Phase 0 (fallback): stage x, compute sigmoid, fuse y ----
            const float* xc = x + ((size_t)b * 4 + cl) * (size_t)CSTRIDE;
#pragma unroll
            for (int k = 0; k < 7; k++) {
                const int i = t + 256 * k;
                if (i < NCOL * 8) {
                    const int col = i >> 3, q = i & 7;
                    const int ih = col / IW, iw = col - ih * IW;
                    const int h = min(h0 + ih, H - 1);
                    const int w = min(w0 + iw, W - 1);
                    const int dbase = dstage + 4 * q;   // always in-bounds
                    const float4 xv = *(const float4*)(xc + (h * W + w) * DD + dbase);
                    const unsigned int pk = yb[col * 2 + (q >> 2)] >> (8 * (q & 3));
                    const float s0 = 1.0f / (1.0f + __expf(-xv.x));
                    const float s1 = 1.0f / (1.0f + __expf(-xv.y));
                    const float s2 = 1.0f / (1.0f + __expf(-xv.z));
                    const float s3 = 1.0f / (1.0f + __expf(-xv.w));
                    Half4 hv;
                    hv.x = __float2half(((int)((pk >> 0) & 3u) == cl) ? s0 : -s0);
                    hv.y = __float2half(((int)((pk >> 2) & 3u) == cl) ? s1 : -s1);
                    hv.z = __float2half(((int)((pk >> 4) & 3u) == cl) ? s2 : -s2);
                    hv.w = __float2half(((int)((pk >> 6) & 3u) == cl) ? s3 : -s3);
                    const int g  = ((ih & 1) << 2) | ((ih >> 1) & 3);
                    const int cp = ((col & 1) << 2) | (q >> 1);
                    const int lofs = ((col >> 1) << 7) | ((cp ^ g) << 4) | ((q & 1) << 3);
                    *(Half4*)((char*)u.vs + lofs) = hv;
                }
            }
        }
        __syncthreads();

        // ---- Prefetch class cl+1 staging into regs (T14 issue-early):
        // independent of all LDS; lands during Phases A+B+C. The ds_write
        // that consumes them waits at the next loop iteration's Phase 0.
        if (PRE && cl < 3) {
            const __half* xscn = xs + ((size_t)b * 4 + cl + 1) * (size_t)CSTRIDE;
            pf0 = *(const uint4*)(xscn + gof0);
            pf1 = *(const uint4*)(xscn + gof1);
            pf2 = *(const uint4*)(xscn + gof2);
            if (gof3 >= 0) pf3 = *(const uint4*)(xscn + gof3);
        }

        // ---- Phase A: W-window, packed f16 over dd-pairs. 210 items (ih,dp).
        if (actA) {
            const __half2 z2 = __float2half2_rn(0.f);
            __half2 v2[IW];
#pragma unroll
            for (int iw = 0; iw < IW; iw++) {
                const int ad = ((iw & 1) ? (baseE ^ 64) : baseE) + (iw >> 1) * 128;
                v2[iw] = *(const __half2*)((const char*)u.vs + ad);
            }
            __half2 sm = z2, sp = z2, sq = z2;
#pragma unroll
            for (int iw = 0; iw < WINS; iw++) {
                __half2 p, m;
                pmask(v2[iw], p, m);
                sm = __hadd2(sm, m);
                sp = __hadd2(sp, p);
                sq = __hfma2(p, v2[iw], sq);
            }
            int o = oA0;
            *(__half2*)&sA0[o] = sm;
            *(__half2*)&sA1[o] = sp;
            *(__half2*)&sA2[o] = sq;
#pragma unroll
            for (int wo = 1; wo < TW; wo++) {
                const __half2 a = v2[wo + 6], bb = v2[wo - 1];
                __half2 pa, ma, pb, mb;
                pmask(a, pa, ma);
                pmask(bb, pb, mb);
                sm = __hadd2(sm, __hsub2(ma, mb));
                sp = __hadd2(sp, __hsub2(pa, pb));
                sq = __hadd2(sq, __hsub2(__hmul2(pa, a), __hmul2(pb, bb)));
                o += SAS;
                *(__half2*)&sA0[o] = sm;
                *(__half2*)&sA1[o] = sp;
                *(__half2*)&sA2[o] = sq;
            }
        }
        __syncthreads();   // sA ready; vs reads retired before sb overwrites union

        // ---- Phase B: H-window, packed f16 over dd-pairs. 240 items ----
        if (actB) {
            __half2 a0[10], a1[10], a2[10];
#pragma unroll
            for (int k = 0; k < 10; k++) {
                const int idx = idxB0 + k * (TW * SAS);
                a0[k] = *(const __half2*)&sA0[idx];
                a1[k] = *(const __half2*)&sA1[idx];
                a2[k] = *(const __half2*)&sA2[idx];
            }
            __half2 s0 = a0[0], s1 = a1[0], s2 = a2[0];
#pragma unroll
            for (int k = 1; k < WINS; k++) {
                s0 = __hadd2(s0, a0[k]);
                s1 = __hadd2(s1, a1[k]);
                s2 = __hadd2(s2, a2[k]);
            }
            int o = oB0;
            u.sb2[o] = s0; u.sb2[o + 1] = s1; u.sb2[o + 2] = s2;
#pragma unroll
            for (int k = 1; k < 4; k++) {
                s0 = __hadd2(s0, __hsub2(a0[k + 6], a0[k - 1]));
                s1 = __hadd2(s1, __hsub2(a1[k + 6], a1[k - 1]));
                s2 = __hadd2(s2, __hsub2(a2[k + 6], a2[k - 1]));
                o += TW * SBC;
                u.sb2[o] = s0; u.sb2[o + 1] = s1; u.sb2[o + 2] = s2;
            }
        }
        __syncthreads();

        // ---- Phase C: D-window, slide 6 outputs. Full 256 threads (ho,wo,dq).
        if (actC) {
            float b0[12], b1[12], b2[12];
#pragma unroll
            for (int k = 0; k < 6; k++) {
                float2 f;
                f = __half22float2(u.sb2[base2C + 3 * k + 0]);
                b0[2 * k] = f.x; b0[2 * k + 1] = f.y;
                f = __half22float2(u.sb2[base2C + 3 * k + 1]);
                b1[2 * k] = f.x; b1[2 * k + 1] = f.y;
                f = __half22float2(u.sb2[base2C + 3 * k + 2]);
                b2[2 * k] = f.x; b2[2 * k + 1] = f.y;
            }
            float s0 = 0.f, s1 = 0.f, s2 = 0.f;
#pragma unroll
            for (int k = 0; k < WINS; k++) { s0 += b0[k]; s1 += b1[k]; s2 += b2[k]; }
            const int od0 = 6 * dqC;
#pragma unroll
            for (int k = 0; k < 6; k++) {
                if (k > 0) {
                    s0 += b0[k + 6] - b0[k - 1];
                    s1 += b1[k + 6] - b1[k - 1];
                    s2 += b2[k + 6] - b2[k - 1];
                }
                if (od0 + k < odmax) lsum += sval(s0, s1, s2);
            }
        }
        __syncthreads();   // retire sb reads before next class overwrites union
    }

    // wave(64) shuffle reduce, then cross-wave via LDS, one atomic per block
#pragma unroll
    for (int off = 32; off > 0; off >>= 1) lsum += __shfl_down(lsum, off, 64);
    const int wave = t >> 6;
    if ((t & 63) == 0) wsum[wave] = lsum;
    __syncthreads();
    if (t == 0) {
        const float s = wsum[0] + wsum[1] + wsum[2] + wsum[3];
        atomicAdd(acc, (double)s);
    }
}

__global__ void structure_loss_finalize(const double* __restrict__ acc,
                                        float* __restrict__ out) {
    out[0] = 1.0f - (float)(acc[0] / 17075520.0);   // 8*154*154*90
}

extern "C" void kernel_launch(void* const* d_in, const int* in_sizes, int n_in,
                              void* d_out, int out_size, void* d_ws, size_t ws_size,
                              hipStream_t stream) {
    const float* x = (const float*)d_in[0];
    const int*   y = (const int*)d_in[1];
    double* acc = (double*)d_ws;
    __half* xs = (__half*)((char*)d_ws + 16);

    const size_t need = 16 + (size_t)8 * CSTRIDE * sizeof(__half);   // ~39.3 MB
    dim3 grid(DTILES, WTILES, 2 * HTILES);   // (4, 20, 40) = 3,200 blocks

    if (ws_size >= need) {
        // prepass zeroes acc -> 3 dispatches total
        sigmoid_prepass<<<dim3(2400, 2), 256, 0, stream>>>(x, y, xs, acc);
        structure_loss_main<true><<<grid, 256, 0, stream>>>(x, y, xs, acc);
    } else {
        (void)hipMemsetAsync(d_ws, 0, sizeof(double), stream);
        structure_loss_main<false><<<grid, 256, 0, stream>>>(x, y, xs, acc);
    }
    structure_loss_finalize<<<1, 1, 0, stream>>>(acc, (float*)d_out);
}